// Round 3
// baseline (291.874 us; speedup 1.0000x reference)
//
#include <hip/hip_runtime.h>
#include <hip/hip_cooperative_groups.h>
#include <cstdint>

namespace cg = cooperative_groups;

#define FMAPX 188
#define NCELLS (FMAPX * FMAPX)   // 35344
#define KMAX 512
#define NCLS 3
#define IDX_INF 0x7fffffff
#define GRID 512
#define TPB 256
#define TTOT (GRID * TPB)        // 131072 threads

// ---------------------------------------------------------------------------
// Workspace (everything written each call before being read)
// ---------------------------------------------------------------------------
struct WS {
    float cxi[KMAX], cyi[KMAX];   // (float)int centers
    float a[KMAX];                // 1/(2 sigma^2)      (0 for invalid)
    float dm[KMAX];               // (float)min sq dist (0 for invalid)
    float fc[KMAX];               // norm factor        (0 for invalid)
    int   cls[KMAX];              // class id
    int   minidx[NCELLS];         // per-cell smallest voxel index
    float H[NCLS][NCELLS];        // per-cell heatmap
};

__device__ __forceinline__ void scan_cell(const int* __restrict__ minidx,
                                          int x, int y, int cix, int ciy,
                                          unsigned long long& best) {
    int mi = minidx[x * FMAPX + y];
    if (mi != IDX_INF) {
        int dx = x - cix, dy = y - ciy;
        unsigned int d = (unsigned int)(dx * dx + dy * dy);
        unsigned long long key = ((unsigned long long)d << 32) | (unsigned int)mi;
        if (key < best) best = key;
    }
}

__global__ __launch_bounds__(TPB) void k_all(const float* __restrict__ gt,
                                             const int* __restrict__ si,
                                             int K, int N, WS* __restrict__ ws,
                                             float* __restrict__ out) {
    cg::grid_group grid = cg::this_grid();
    const int gtid = blockIdx.x * TPB + threadIdx.x;

    // ---- phase 0: init cell map -------------------------------------------
    for (int c = gtid; c < NCELLS; c += TTOT) ws->minidx[c] = IDX_INF;
    grid.sync();

    // ---- phase 1: build per-cell min voxel index --------------------------
    for (int n = gtid; n < N; n += TTOT) {
        int2 v = ((const int2*)si)[n];
        atomicMin(&ws->minidx[v.x * FMAPX + v.y], n);
    }
    grid.sync();

    // ---- phase 2: per-object setup + ring argmin + box outputs ------------
    if (gtid < K) {
        const int t = gtid;
        const float* g = gt + t * 8;
        float ddx = g[3], ddy = g[4];
        int val = ((ddx > 0.0f) && (ddy > 0.0f)) ? 1 : 0;

        float coord_x = (g[0] + 75.2f) * (1.0f / 0.8f);
        coord_x = fminf(fmaxf(coord_x, 0.0f), (float)FMAPX - 0.5f);
        float coord_y = (g[1] + 75.2f) * (1.0f / 0.8f);
        coord_y = fminf(fmaxf(coord_y, 0.0f), (float)FMAPX - 0.5f);
        int cix = (int)coord_x;
        int ciy = (int)coord_y;

        float h = ddx * (1.0f / 0.8f);
        float w = ddy * (1.0f / 0.8f);
        const float ov = 0.1f;
        float b1 = h + w;
        float c1 = w * h * (1.0f - ov) / (1.0f + ov);
        float r1 = (b1 + sqrtf(b1 * b1 - 4.0f * c1)) * 0.5f;
        float b2 = 2.0f * (h + w);
        float c2 = (1.0f - ov) * w * h;
        float r2 = (b2 + sqrtf(b2 * b2 - 16.0f * c2)) * 0.125f;
        float a3 = 4.0f * ov;
        float b3 = -2.0f * ov * (h + w);
        float c3 = (ov - 1.0f) * w * h;
        float r3 = (-b3 + sqrtf(b3 * b3 - 4.0f * a3 * c3)) / (2.0f * a3);
        float r = fminf(fminf(r1, r2), r3);
        int radius = (int)r;
        if (radius < 2) radius = 2;
        float sigma = (2.0f * (float)radius + 1.0f) * (1.0f / 6.0f);
        float a = 1.0f / (2.0f * sigma * sigma);

        // exact expanding-Chebyshev-ring argmin over occupied cells
        const int* __restrict__ minidx = ws->minidx;
        unsigned long long best = ~0ull;
        for (int rr = 0; rr <= 2 * FMAPX; ++rr) {
            if (best != ~0ull &&
                (unsigned long long)rr * (unsigned long long)rr > (best >> 32)) break;
            if (rr == 0) {
                scan_cell(minidx, cix, ciy, cix, ciy, best);
            } else {
                int x0 = cix - rr, x1 = cix + rr;
                int ylo = max(ciy - rr, 0), yhi = min(ciy + rr, FMAPX - 1);
                if (x0 >= 0)    for (int y = ylo; y <= yhi; ++y) scan_cell(minidx, x0, y, cix, ciy, best);
                if (x1 < FMAPX) for (int y = ylo; y <= yhi; ++y) scan_cell(minidx, x1, y, cix, ciy, best);
                int y0 = ciy - rr, y1 = ciy + rr;
                int xlo = max(x0 + 1, 0), xhi = min(x1 - 1, FMAPX - 1);
                if (y0 >= 0)    for (int x = xlo; x <= xhi; ++x) scan_cell(minidx, x, y0, cix, ciy, best);
                if (y1 < FMAPX) for (int x = xlo; x <= xhi; ++x) scan_cell(minidx, x, y1, cix, ciy, best);
            }
        }
        int ind = (int)(best & 0xffffffffull);
        float dminf = (float)(unsigned int)(best >> 32);
        float factor = fminf(__expf(-dminf * a) * 1e6f, 1.0f);
        if (!val) { a = 0.0f; dminf = 0.0f; factor = 0.0f; }

        ws->cxi[t] = (float)cix;
        ws->cyi[t] = (float)ciy;
        ws->a[t]   = a;
        ws->dm[t]  = dminf;
        ws->fc[t]  = factor;
        ws->cls[t] = (int)(g[7] - 1.0f);

        float nx = (float)si[2 * ind];
        float ny = (float)si[2 * ind + 1];
        float* rb = out + 3 * N + t * 8;
        rb[0] = val ? (coord_x - nx) : 0.0f;
        rb[1] = val ? (coord_y - ny) : 0.0f;
        rb[2] = val ? g[2] : 0.0f;
        rb[3] = val ? logf(g[3]) : 0.0f;
        rb[4] = val ? logf(g[4]) : 0.0f;
        rb[5] = val ? logf(g[5]) : 0.0f;
        rb[6] = val ? cosf(g[6]) : 0.0f;
        rb[7] = val ? sinf(g[6]) : 0.0f;
        out[3 * N + 8 * K + t] = (float)ind;          // inds
        out[3 * N + 9 * K + t] = val ? 1.0f : 0.0f;   // valid
    }
    grid.sync();

    // ---- phase 3: per-cell heatmap (objects staged in LDS) ----------------
    __shared__ float cxL[KMAX], cyL[KMAX], aL[KMAX], dmL[KMAX], fcL[KMAX];
    __shared__ int   clsL[KMAX];
    for (int i = threadIdx.x; i < K; i += TPB) {
        cxL[i]  = ws->cxi[i];
        cyL[i]  = ws->cyi[i];
        aL[i]   = ws->a[i];
        dmL[i]  = ws->dm[i];
        fcL[i]  = ws->fc[i];
        clsL[i] = ws->cls[i];
    }
    __syncthreads();

    for (int c = gtid; c < NCELLS; c += TTOT) {
        int cxi = c / FMAPX;
        float cx = (float)cxi;
        float cy = (float)(c - cxi * FMAPX);
        float m0 = 0.0f, m1 = 0.0f, m2 = 0.0f;
        #pragma unroll 4
        for (int i = 0; i < K; i++) {
            float dx = cx - cxL[i], dy = cy - cyL[i];
            float dist = fmaf(dx, dx, dy * dy);
            float gv = __expf((dmL[i] - dist) * aL[i]) * fcL[i];
            int cl = clsL[i];
            m0 = fmaxf(m0, cl == 0 ? gv : 0.0f);
            m1 = fmaxf(m1, cl == 1 ? gv : 0.0f);
            m2 = fmaxf(m2, cl == 2 ? gv : 0.0f);
        }
        ws->H[0][c] = m0;
        ws->H[1][c] = m1;
        ws->H[2][c] = m2;
    }
    grid.sync();

    // ---- phase 4: per-voxel gather ----------------------------------------
    for (int n = gtid; n < N; n += TTOT) {
        int2 v = ((const int2*)si)[n];
        int c = v.x * FMAPX + v.y;
        out[n]         = ws->H[0][c];
        out[N + n]     = ws->H[1][c];
        out[2 * N + n] = ws->H[2][c];
    }
}

// ---------------------------------------------------------------------------
extern "C" void kernel_launch(void* const* d_in, const int* in_sizes, int n_in,
                              void* d_out, int out_size, void* d_ws, size_t ws_size,
                              hipStream_t stream) {
    const float* gt = (const float*)d_in[0];
    const int*   si = (const int*)d_in[1];
    int K = in_sizes[0] / 8;     // 500
    int N = in_sizes[1] / 2;     // 150000
    WS* ws = (WS*)d_ws;
    float* out = (float*)d_out;

    void* args[] = { (void*)&gt, (void*)&si, (void*)&K, (void*)&N,
                     (void*)&ws, (void*)&out };
    hipLaunchCooperativeKernel((const void*)k_all, dim3(GRID), dim3(TPB),
                               args, 0, stream);
}

// Round 4
// 100.344 us; speedup vs baseline: 2.9087x; 2.9087x over previous
//
#include <hip/hip_runtime.h>
#include <cstdint>

#define FMAPX 188
#define NCELLS (FMAPX * FMAPX)   // 35344
#define KMAX 512
#define NCLS 3
#define IDX_INF 0x7f7f7f7f       // memset(0x7f) pattern; > any voxel index
#define TPB 256
#define LOG2E 1.4426950408889634f
#define LOG2_1E6 19.931568569324174f

struct WS {
    int minidx[NCELLS];          // per-cell smallest voxel index (or IDX_INF)
};

// ---------------------------------------------------------------------------
// 1. build per-cell min voxel index (minidx pre-initialized via memsetAsync)
// ---------------------------------------------------------------------------
__global__ __launch_bounds__(TPB) void k_build(const int* __restrict__ si, int N,
                                               WS* __restrict__ ws) {
    int n = blockIdx.x * TPB + threadIdx.x;
    if (n >= N) return;
    int2 v = ((const int2*)si)[n];
    atomicMin(&ws->minidx[v.x * FMAPX + v.y], n);
}

// ---------------------------------------------------------------------------
// 2. fused: per-block object prologue (setup + ring argmin + LDS bucketing),
//    block 0 writes box outputs, then per-voxel heatmap straight to out.
// ---------------------------------------------------------------------------
__device__ __forceinline__ void scan_cell(const int* __restrict__ minidx,
                                          int x, int y, int cix, int ciy,
                                          unsigned long long& best) {
    int mi = minidx[x * FMAPX + y];
    if (mi != IDX_INF) {
        int dx = x - cix, dy = y - ciy;
        unsigned int d = (unsigned int)(dx * dx + dy * dy);
        unsigned long long key = ((unsigned long long)d << 32) | (unsigned int)mi;
        if (key < best) best = key;
    }
}

__global__ __launch_bounds__(TPB) void k_fused(const float* __restrict__ gt,
                                               const int* __restrict__ si,
                                               int K, int N,
                                               const WS* __restrict__ ws,
                                               float* __restrict__ out) {
    __shared__ int cnt[NCLS];
    __shared__ int offS[NCLS + 1];
    __shared__ float4 prm[KMAX];      // bucketed (cx, cy, -a2, b2)

    const int tid = threadIdx.x;
    if (tid < NCLS) cnt[tid] = 0;
    __syncthreads();

    // ---- phase A: per-object compute (each block redundantly; 2 objs/thread)
    int   myrank[2] = { -1, -1 };
    int   mycls[2]  = { 0, 0 };
    float4 myprm[2];

    #pragma unroll
    for (int it = 0; it < 2; ++it) {
        int t = tid + it * TPB;
        if (t >= K) break;
        const float* g = gt + t * 8;
        float ddx = g[3], ddy = g[4];
        int val = ((ddx > 0.0f) && (ddy > 0.0f)) ? 1 : 0;

        float coord_x = (g[0] + 75.2f) * (1.0f / 0.8f);
        coord_x = fminf(fmaxf(coord_x, 0.0f), (float)FMAPX - 0.5f);
        float coord_y = (g[1] + 75.2f) * (1.0f / 0.8f);
        coord_y = fminf(fmaxf(coord_y, 0.0f), (float)FMAPX - 0.5f);
        int cix = (int)coord_x;
        int ciy = (int)coord_y;

        float h = ddx * (1.0f / 0.8f);
        float w = ddy * (1.0f / 0.8f);
        const float ov = 0.1f;
        float b1 = h + w;
        float c1 = w * h * (1.0f - ov) / (1.0f + ov);
        float r1 = (b1 + sqrtf(b1 * b1 - 4.0f * c1)) * 0.5f;
        float b2_ = 2.0f * (h + w);
        float c2 = (1.0f - ov) * w * h;
        float r2 = (b2_ + sqrtf(b2_ * b2_ - 16.0f * c2)) * 0.125f;
        float a3 = 4.0f * ov;
        float b3 = -2.0f * ov * (h + w);
        float c3 = (ov - 1.0f) * w * h;
        float r3 = (-b3 + sqrtf(b3 * b3 - 4.0f * a3 * c3)) / (2.0f * a3);
        float r = fminf(fminf(r1, r2), r3);
        int radius = (int)r;
        if (radius < 2) radius = 2;
        float sigma = (2.0f * (float)radius + 1.0f) * (1.0f / 6.0f);
        float a  = 1.0f / (2.0f * sigma * sigma);
        float a2 = a * LOG2E;

        // exact expanding-Chebyshev-ring argmin over occupied cells
        const int* __restrict__ minidx = ws->minidx;
        unsigned long long best = ~0ull;
        for (int rr = 0; rr <= 2 * FMAPX; ++rr) {
            if (best != ~0ull &&
                (unsigned long long)rr * (unsigned long long)rr > (best >> 32)) break;
            if (rr == 0) {
                scan_cell(minidx, cix, ciy, cix, ciy, best);
            } else {
                int x0 = cix - rr, x1 = cix + rr;
                int ylo = max(ciy - rr, 0), yhi = min(ciy + rr, FMAPX - 1);
                if (x0 >= 0)    for (int y = ylo; y <= yhi; ++y) scan_cell(minidx, x0, y, cix, ciy, best);
                if (x1 < FMAPX) for (int y = ylo; y <= yhi; ++y) scan_cell(minidx, x1, y, cix, ciy, best);
                int y0 = ciy - rr, y1 = ciy + rr;
                int xlo = max(x0 + 1, 0), xhi = min(x1 - 1, FMAPX - 1);
                if (y0 >= 0)    for (int x = xlo; x <= xhi; ++x) scan_cell(minidx, x, y0, cix, ciy, best);
                if (y1 < FMAPX) for (int x = xlo; x <= xhi; ++x) scan_cell(minidx, x, y1, cix, ciy, best);
            }
        }
        int ind = (int)(best & 0xffffffffull);
        float dminf = (float)(unsigned int)(best >> 32);

        // normalized gaussian: gv = 2^(b2 - dist*a2), b2 = min(dmin*a2, log2(1e6))
        float b2 = fminf(dminf * a2, LOG2_1E6);

        int cl = (int)(g[7] - 1.0f);
        mycls[it] = cl;
        myprm[it] = make_float4((float)cix, (float)ciy, -a2, b2);
        if (val && cl >= 0 && cl < NCLS)
            myrank[it] = atomicAdd(&cnt[cl], 1);

        if (blockIdx.x == 0) {
            // box outputs written once (block 0 only)
            float nx = (float)si[2 * ind];
            float ny = (float)si[2 * ind + 1];
            float* rb = out + 3 * N + t * 8;
            rb[0] = val ? (coord_x - nx) : 0.0f;
            rb[1] = val ? (coord_y - ny) : 0.0f;
            rb[2] = val ? g[2] : 0.0f;
            rb[3] = val ? logf(g[3]) : 0.0f;
            rb[4] = val ? logf(g[4]) : 0.0f;
            rb[5] = val ? logf(g[5]) : 0.0f;
            rb[6] = val ? cosf(g[6]) : 0.0f;
            rb[7] = val ? sinf(g[6]) : 0.0f;
            out[3 * N + 8 * K + t] = (float)ind;          // inds
            out[3 * N + 9 * K + t] = val ? 1.0f : 0.0f;   // valid
        }
    }
    __syncthreads();
    if (tid == 0) {
        offS[0] = 0;
        offS[1] = cnt[0];
        offS[2] = cnt[0] + cnt[1];
        offS[3] = cnt[0] + cnt[1] + cnt[2];
    }
    __syncthreads();
    #pragma unroll
    for (int it = 0; it < 2; ++it)
        if (myrank[it] >= 0) prm[offS[mycls[it]] + myrank[it]] = myprm[it];
    __syncthreads();

    // ---- phase B: per-voxel heatmap ---------------------------------------
    int n = blockIdx.x * TPB + tid;
    if (n >= N) return;
    int2 v = ((const int2*)si)[n];
    float cx = (float)v.x;
    float cy = (float)v.y;

    #pragma unroll
    for (int c = 0; c < NCLS; ++c) {
        int i = offS[c], e = offS[c + 1];
        float mm = 0.0f;
        for (; i < e; ++i) {
            float4 p = prm[i];
            float dx = cx - p.x, dy = cy - p.y;
            float dist = fmaf(dx, dx, dy * dy);
            mm = fmaxf(mm, __builtin_amdgcn_exp2f(fmaf(p.z, dist, p.w)));
        }
        out[c * N + n] = mm;
    }
}

// ---------------------------------------------------------------------------
extern "C" void kernel_launch(void* const* d_in, const int* in_sizes, int n_in,
                              void* d_out, int out_size, void* d_ws, size_t ws_size,
                              hipStream_t stream) {
    const float* gt = (const float*)d_in[0];
    const int*   si = (const int*)d_in[1];
    int K = in_sizes[0] / 8;     // 500
    int N = in_sizes[1] / 2;     // 150000
    WS* ws = (WS*)d_ws;
    float* out = (float*)d_out;

    hipMemsetAsync(ws->minidx, 0x7f, NCELLS * sizeof(int), stream);
    hipLaunchKernelGGL(k_build, dim3((N + TPB - 1) / TPB), dim3(TPB), 0, stream, si, N, ws);
    hipLaunchKernelGGL(k_fused, dim3((N + TPB - 1) / TPB), dim3(TPB), 0, stream,
                       gt, si, K, N, ws, out);
}

// Round 5
// 73.318 us; speedup vs baseline: 3.9810x; 1.3686x over previous
//
#include <hip/hip_runtime.h>
#include <cstdint>

#define FMAPX 188
#define NCELLS (FMAPX * FMAPX)   // 35344
#define NCLS 3
#define IDX_INF 0x7f7f7f7f       // memset(0x7f) pattern; > any voxel index
#define TPB 256
#define LOG2E 1.4426950408889634f
#define LOG2_1E6 19.931568569324174f
#define CUT 13.0f                // drop gaussian tails below 2^-13 (~1.2e-4)

struct WS {
    int   minidx[NCELLS];        // per-cell smallest voxel index (or IDX_INF)
    float H[NCLS][NCELLS];       // per-class per-cell heatmap (atomicMax'd)
};

// ---------------------------------------------------------------------------
// 1. build per-cell min voxel index (minidx pre-init via memsetAsync 0x7f)
//    + zero the H maps with the same grid's spare coverage
// ---------------------------------------------------------------------------
__global__ __launch_bounds__(TPB) void k_build(const int* __restrict__ si, int N,
                                               WS* __restrict__ ws) {
    int n = blockIdx.x * TPB + threadIdx.x;
    if (n < NCLS * NCELLS) ((float*)ws->H)[n] = 0.0f;
    if (n >= N) return;
    int2 v = ((const int2*)si)[n];
    atomicMin(&ws->minidx[v.x * FMAPX + v.y], n);
}

// ---------------------------------------------------------------------------
// 2. wave-per-object: setup + exact ring argmin + box outputs + disk scatter
// ---------------------------------------------------------------------------
__device__ __forceinline__ void scan_cell(const int* __restrict__ minidx,
                                          int x, int y, int cix, int ciy,
                                          unsigned long long& best) {
    int mi = minidx[x * FMAPX + y];
    if (mi != IDX_INF) {
        int dx = x - cix, dy = y - ciy;
        unsigned int d = (unsigned int)(dx * dx + dy * dy);
        unsigned long long key = ((unsigned long long)d << 32) | (unsigned int)mi;
        if (key < best) best = key;
    }
}

__global__ __launch_bounds__(TPB) void k_obj(const float* __restrict__ gt,
                                             const int* __restrict__ si,
                                             int K, int N,
                                             WS* __restrict__ ws,
                                             float* __restrict__ out) {
    int gtid = blockIdx.x * TPB + threadIdx.x;
    int t    = gtid >> 6;        // one wave per object
    int lane = gtid & 63;
    if (t >= K) return;

    // ---- per-object setup (all 64 lanes redundantly; uniform data) --------
    const float* g = gt + t * 8;
    float ddx = g[3], ddy = g[4];
    int val = ((ddx > 0.0f) && (ddy > 0.0f)) ? 1 : 0;

    float coord_x = (g[0] + 75.2f) * (1.0f / 0.8f);
    coord_x = fminf(fmaxf(coord_x, 0.0f), (float)FMAPX - 0.5f);
    float coord_y = (g[1] + 75.2f) * (1.0f / 0.8f);
    coord_y = fminf(fmaxf(coord_y, 0.0f), (float)FMAPX - 0.5f);
    int cix = (int)coord_x;
    int ciy = (int)coord_y;

    float h = ddx * (1.0f / 0.8f);
    float w = ddy * (1.0f / 0.8f);
    const float ov = 0.1f;
    float b1 = h + w;
    float c1 = w * h * (1.0f - ov) / (1.0f + ov);
    float r1 = (b1 + sqrtf(b1 * b1 - 4.0f * c1)) * 0.5f;
    float b2_ = 2.0f * (h + w);
    float c2 = (1.0f - ov) * w * h;
    float r2 = (b2_ + sqrtf(b2_ * b2_ - 16.0f * c2)) * 0.125f;
    float a3 = 4.0f * ov;
    float b3 = -2.0f * ov * (h + w);
    float c3 = (ov - 1.0f) * w * h;
    float r3 = (-b3 + sqrtf(b3 * b3 - 4.0f * a3 * c3)) / (2.0f * a3);
    float r = fminf(fminf(r1, r2), r3);
    int radius = (int)r;
    if (radius < 2) radius = 2;
    float sigma = (2.0f * (float)radius + 1.0f) * (1.0f / 6.0f);
    float a  = 1.0f / (2.0f * sigma * sigma);
    float a2 = a * LOG2E;

    // ---- exact expanding-Chebyshev-ring argmin (redundant across lanes) ---
    const int* __restrict__ minidx = ws->minidx;
    unsigned long long best = ~0ull;
    for (int rr = 0; rr <= 2 * FMAPX; ++rr) {
        if (best != ~0ull &&
            (unsigned long long)rr * (unsigned long long)rr > (best >> 32)) break;
        if (rr == 0) {
            scan_cell(minidx, cix, ciy, cix, ciy, best);
        } else {
            int x0 = cix - rr, x1 = cix + rr;
            int ylo = max(ciy - rr, 0), yhi = min(ciy + rr, FMAPX - 1);
            if (x0 >= 0)    for (int y = ylo; y <= yhi; ++y) scan_cell(minidx, x0, y, cix, ciy, best);
            if (x1 < FMAPX) for (int y = ylo; y <= yhi; ++y) scan_cell(minidx, x1, y, cix, ciy, best);
            int y0 = ciy - rr, y1 = ciy + rr;
            int xlo = max(x0 + 1, 0), xhi = min(x1 - 1, FMAPX - 1);
            if (y0 >= 0)    for (int x = xlo; x <= xhi; ++x) scan_cell(minidx, x, y0, cix, ciy, best);
            if (y1 < FMAPX) for (int x = xlo; x <= xhi; ++x) scan_cell(minidx, x, y1, cix, ciy, best);
        }
    }
    int ind = (int)(best & 0xffffffffull);
    float dminf = (float)(unsigned int)(best >> 32);
    float b2 = fminf(dminf * a2, LOG2_1E6);   // log2 of norm factor clamp

    // ---- box outputs (lane 0) ---------------------------------------------
    if (lane == 0) {
        float nx = (float)si[2 * ind];
        float ny = (float)si[2 * ind + 1];
        float* rb = out + 3 * N + t * 8;
        rb[0] = val ? (coord_x - nx) : 0.0f;
        rb[1] = val ? (coord_y - ny) : 0.0f;
        rb[2] = val ? g[2] : 0.0f;
        rb[3] = val ? logf(g[3]) : 0.0f;
        rb[4] = val ? logf(g[4]) : 0.0f;
        rb[5] = val ? logf(g[5]) : 0.0f;
        rb[6] = val ? cosf(g[6]) : 0.0f;
        rb[7] = val ? sinf(g[6]) : 0.0f;
        out[3 * N + 8 * K + t] = (float)ind;          // inds
        out[3 * N + 9 * K + t] = val ? 1.0f : 0.0f;   // valid
    }

    // ---- disk scatter into per-class cell map -----------------------------
    if (!val) return;
    int cl = (int)(g[7] - 1.0f);
    if (cl < 0 || cl >= NCLS) return;

    int rc = (int)ceilf(sqrtf((b2 + CUT) / a2));
    int x0 = max(cix - rc, 0), x1 = min(cix + rc, FMAPX - 1);
    int y0 = max(ciy - rc, 0), y1 = min(ciy + rc, FMAPX - 1);
    int hh = y1 - y0 + 1;
    int tot = (x1 - x0 + 1) * hh;
    unsigned int* __restrict__ Hc = (unsigned int*)ws->H[cl];

    for (int i = lane; i < tot; i += 64) {
        int xx = x0 + i / hh;
        int yy = y0 + i % hh;
        int dxi = xx - cix, dyi = yy - ciy;
        float dist = (float)(dxi * dxi + dyi * dyi);
        float arg = fmaf(-a2, dist, b2);
        if (arg > -CUT) {
            float gv = __builtin_amdgcn_exp2f(arg);
            atomicMax(&Hc[xx * FMAPX + yy], __float_as_uint(gv));
        }
    }
}

// ---------------------------------------------------------------------------
// 3. per-voxel gather
// ---------------------------------------------------------------------------
__global__ __launch_bounds__(TPB) void k_gather(const int* __restrict__ si, int N,
                                                const WS* __restrict__ ws,
                                                float* __restrict__ out) {
    int n = blockIdx.x * TPB + threadIdx.x;
    if (n >= N) return;
    int2 v = ((const int2*)si)[n];
    int c = v.x * FMAPX + v.y;
    out[n]         = ws->H[0][c];
    out[N + n]     = ws->H[1][c];
    out[2 * N + n] = ws->H[2][c];
}

// ---------------------------------------------------------------------------
extern "C" void kernel_launch(void* const* d_in, const int* in_sizes, int n_in,
                              void* d_out, int out_size, void* d_ws, size_t ws_size,
                              hipStream_t stream) {
    const float* gt = (const float*)d_in[0];
    const int*   si = (const int*)d_in[1];
    int K = in_sizes[0] / 8;     // 500
    int N = in_sizes[1] / 2;     // 150000
    WS* ws = (WS*)d_ws;
    float* out = (float*)d_out;

    hipMemsetAsync(ws->minidx, 0x7f, NCELLS * sizeof(int), stream);
    hipLaunchKernelGGL(k_build, dim3((N + TPB - 1) / TPB), dim3(TPB), 0, stream, si, N, ws);
    hipLaunchKernelGGL(k_obj, dim3((K * 64 + TPB - 1) / TPB), dim3(TPB), 0, stream,
                       gt, si, K, N, ws, out);
    hipLaunchKernelGGL(k_gather, dim3((N + TPB - 1) / TPB), dim3(TPB), 0, stream,
                       si, N, ws, out);
}

// Round 6
// 73.296 us; speedup vs baseline: 3.9821x; 1.0003x over previous
//
#include <hip/hip_runtime.h>
#include <cstdint>

#define FMAPX 188
#define NCELLS (FMAPX * FMAPX)   // 35344
#define NCLS 3
#define IDX_INF 0x7f7f7f7f       // memset(0x7f) pattern; > any voxel index
#define TPB 256
#define LOG2E 1.4426950408889634f
#define LOG2_1E6 19.931568569324174f
#define CUT 13.0f                // drop gaussian tails below 2^-13 (~1.2e-4)

// H stored as enc = 0x7fffffff - float_bits(gv): monotone-inverted so
// atomicMin == float max, and the empty sentinel is the same 0x7f7f7f7f
// as minidx -> ONE memset covers the whole workspace. Empty decodes to
// uint_as_float(0x00808080) = 1.2e-38 ~= 0.
struct WS {
    int      minidx[NCELLS];     // per-cell smallest voxel index (or IDX_INF)
    unsigned H[NCLS][NCELLS];    // per-class per-cell heatmap, inverted bits
};

// ---------------------------------------------------------------------------
// 1. build per-cell min voxel index (whole WS pre-init via memsetAsync 0x7f)
//    2 voxels per thread, int4 loads
// ---------------------------------------------------------------------------
__global__ __launch_bounds__(TPB) void k_build(const int* __restrict__ si, int N2,
                                               WS* __restrict__ ws) {
    int i = blockIdx.x * TPB + threadIdx.x;
    if (i >= N2) return;
    int4 v = ((const int4*)si)[i];
    int n = i * 2;
    atomicMin(&ws->minidx[v.x * FMAPX + v.y], n);
    atomicMin(&ws->minidx[v.z * FMAPX + v.w], n + 1);
}

// ---------------------------------------------------------------------------
// 2. wave-per-object: setup + exact ring argmin + box outputs + disk scatter
// ---------------------------------------------------------------------------
__device__ __forceinline__ void scan_cell(const int* __restrict__ minidx,
                                          int x, int y, int cix, int ciy,
                                          unsigned long long& best) {
    int mi = minidx[x * FMAPX + y];
    if (mi != IDX_INF) {
        int dx = x - cix, dy = y - ciy;
        unsigned int d = (unsigned int)(dx * dx + dy * dy);
        unsigned long long key = ((unsigned long long)d << 32) | (unsigned int)mi;
        if (key < best) best = key;
    }
}

__global__ __launch_bounds__(TPB) void k_obj(const float* __restrict__ gt,
                                             const int* __restrict__ si,
                                             int K, int N,
                                             WS* __restrict__ ws,
                                             float* __restrict__ out) {
    int gtid = blockIdx.x * TPB + threadIdx.x;
    int t    = gtid >> 6;        // one wave per object
    int lane = gtid & 63;
    if (t >= K) return;

    // ---- per-object setup (all 64 lanes redundantly; uniform data) --------
    const float* g = gt + t * 8;
    float ddx = g[3], ddy = g[4];
    int val = ((ddx > 0.0f) && (ddy > 0.0f)) ? 1 : 0;

    float coord_x = (g[0] + 75.2f) * (1.0f / 0.8f);
    coord_x = fminf(fmaxf(coord_x, 0.0f), (float)FMAPX - 0.5f);
    float coord_y = (g[1] + 75.2f) * (1.0f / 0.8f);
    coord_y = fminf(fmaxf(coord_y, 0.0f), (float)FMAPX - 0.5f);
    int cix = (int)coord_x;
    int ciy = (int)coord_y;

    float h = ddx * (1.0f / 0.8f);
    float w = ddy * (1.0f / 0.8f);
    const float ov = 0.1f;
    float b1 = h + w;
    float c1 = w * h * (1.0f - ov) / (1.0f + ov);
    float r1 = (b1 + sqrtf(b1 * b1 - 4.0f * c1)) * 0.5f;
    float b2_ = 2.0f * (h + w);
    float c2 = (1.0f - ov) * w * h;
    float r2 = (b2_ + sqrtf(b2_ * b2_ - 16.0f * c2)) * 0.125f;
    float a3 = 4.0f * ov;
    float b3 = -2.0f * ov * (h + w);
    float c3 = (ov - 1.0f) * w * h;
    float r3 = (-b3 + sqrtf(b3 * b3 - 4.0f * a3 * c3)) / (2.0f * a3);
    float r = fminf(fminf(r1, r2), r3);
    int radius = (int)r;
    if (radius < 2) radius = 2;
    float sigma = (2.0f * (float)radius + 1.0f) * (1.0f / 6.0f);
    float a  = 1.0f / (2.0f * sigma * sigma);
    float a2 = a * LOG2E;

    // ---- exact expanding-Chebyshev-ring argmin ----------------------------
    const int* __restrict__ minidx = ws->minidx;
    unsigned long long best = ~0ull;
    for (int rr = 0; rr <= 2 * FMAPX; ++rr) {
        if (best != ~0ull &&
            (unsigned long long)rr * (unsigned long long)rr > (best >> 32)) break;
        if (rr == 0) {
            scan_cell(minidx, cix, ciy, cix, ciy, best);
        } else {
            int x0 = cix - rr, x1 = cix + rr;
            int ylo = max(ciy - rr, 0), yhi = min(ciy + rr, FMAPX - 1);
            if (x0 >= 0)    for (int y = ylo; y <= yhi; ++y) scan_cell(minidx, x0, y, cix, ciy, best);
            if (x1 < FMAPX) for (int y = ylo; y <= yhi; ++y) scan_cell(minidx, x1, y, cix, ciy, best);
            int y0 = ciy - rr, y1 = ciy + rr;
            int xlo = max(x0 + 1, 0), xhi = min(x1 - 1, FMAPX - 1);
            if (y0 >= 0)    for (int x = xlo; x <= xhi; ++x) scan_cell(minidx, x, y0, cix, ciy, best);
            if (y1 < FMAPX) for (int x = xlo; x <= xhi; ++x) scan_cell(minidx, x, y1, cix, ciy, best);
        }
    }
    int ind = (int)(best & 0xffffffffull);
    float dminf = (float)(unsigned int)(best >> 32);
    float b2 = fminf(dminf * a2, LOG2_1E6);   // log2 of norm-factor clamp

    // ---- box outputs (lane 0) ---------------------------------------------
    if (lane == 0) {
        float nx = (float)si[2 * ind];
        float ny = (float)si[2 * ind + 1];
        float* rb = out + 3 * N + t * 8;
        rb[0] = val ? (coord_x - nx) : 0.0f;
        rb[1] = val ? (coord_y - ny) : 0.0f;
        rb[2] = val ? g[2] : 0.0f;
        rb[3] = val ? logf(g[3]) : 0.0f;
        rb[4] = val ? logf(g[4]) : 0.0f;
        rb[5] = val ? logf(g[5]) : 0.0f;
        rb[6] = val ? cosf(g[6]) : 0.0f;
        rb[7] = val ? sinf(g[6]) : 0.0f;
        out[3 * N + 8 * K + t] = (float)ind;          // inds
        out[3 * N + 9 * K + t] = val ? 1.0f : 0.0f;   // valid
    }

    // ---- disk scatter into per-class cell map (inverted-bits atomicMin) ---
    if (!val) return;
    int cl = (int)(g[7] - 1.0f);
    if (cl < 0 || cl >= NCLS) return;

    int rc = (int)ceilf(sqrtf((b2 + CUT) / a2));
    int x0 = max(cix - rc, 0), x1 = min(cix + rc, FMAPX - 1);
    int y0 = max(ciy - rc, 0), y1 = min(ciy + rc, FMAPX - 1);
    int hh = y1 - y0 + 1;
    int tot = (x1 - x0 + 1) * hh;
    unsigned int* __restrict__ Hc = ws->H[cl];

    for (int i = lane; i < tot; i += 64) {
        int xx = x0 + i / hh;
        int yy = y0 + i % hh;
        int dxi = xx - cix, dyi = yy - ciy;
        float dist = (float)(dxi * dxi + dyi * dyi);
        float arg = fmaf(-a2, dist, b2);
        if (arg > -CUT) {
            float gv = __builtin_amdgcn_exp2f(arg);
            atomicMin(&Hc[xx * FMAPX + yy], 0x7fffffffu - __float_as_uint(gv));
        }
    }
}

// ---------------------------------------------------------------------------
// 3. per-voxel gather (2 voxels/thread, int4 load, float2 stores)
// ---------------------------------------------------------------------------
__global__ __launch_bounds__(TPB) void k_gather(const int* __restrict__ si, int N2,
                                                const WS* __restrict__ ws,
                                                float* __restrict__ out) {
    int i = blockIdx.x * TPB + threadIdx.x;
    if (i >= N2) return;
    int4 v = ((const int4*)si)[i];
    int c0 = v.x * FMAPX + v.y;
    int c1 = v.z * FMAPX + v.w;
    int n = i * 2;
    int N = N2 * 2;
    #pragma unroll
    for (int c = 0; c < NCLS; ++c) {
        float2 o;
        o.x = __uint_as_float(0x7fffffffu - ws->H[c][c0]);
        o.y = __uint_as_float(0x7fffffffu - ws->H[c][c1]);
        *(float2*)(out + c * N + n) = o;
    }
}

// ---------------------------------------------------------------------------
extern "C" void kernel_launch(void* const* d_in, const int* in_sizes, int n_in,
                              void* d_out, int out_size, void* d_ws, size_t ws_size,
                              hipStream_t stream) {
    const float* gt = (const float*)d_in[0];
    const int*   si = (const int*)d_in[1];
    int K  = in_sizes[0] / 8;    // 500
    int N  = in_sizes[1] / 2;    // 150000
    int N2 = N / 2;              // 75000 (N is even)
    WS* ws = (WS*)d_ws;
    float* out = (float*)d_out;

    hipMemsetAsync(ws, 0x7f, sizeof(WS), stream);
    hipLaunchKernelGGL(k_build, dim3((N2 + TPB - 1) / TPB), dim3(TPB), 0, stream, si, N2, ws);
    hipLaunchKernelGGL(k_obj, dim3((K * 64 + TPB - 1) / TPB), dim3(TPB), 0, stream,
                       gt, si, K, N, ws, out);
    hipLaunchKernelGGL(k_gather, dim3((N2 + TPB - 1) / TPB), dim3(TPB), 0, stream,
                       si, N2, ws, out);
}